// Round 1
// baseline (1840.796 us; speedup 1.0000x reference)
//
#include <hip/hip_runtime.h>

#define TT 512
#define BB 64
#define EE 300
#define HH 150
#define G3 450
#define AT 75

__device__ __forceinline__ float fast_rcp(float x) { return __builtin_amdgcn_rcpf(x); }
__device__ __forceinline__ float sigmoid_f(float x) { return fast_rcp(1.f + __expf(-x)); }
__device__ __forceinline__ float tanh_f(float x) {
  float e = __expf(2.f * x);          // inf for large x -> result 1; 0 for very negative -> -1
  return 1.f - 2.f * fast_rcp(e + 1.f);
}

// ---------------- transpose prep ----------------
__global__ void k_prep(const float* __restrict__ Wih0, const float* __restrict__ Whh0,
                       const float* __restrict__ Wih1, const float* __restrict__ Whh1,
                       const float* __restrict__ W1,   const float* __restrict__ fc1w,
                       float* __restrict__ Wih0T, float* __restrict__ Whh0T,
                       float* __restrict__ Wih1T, float* __restrict__ Whh1T,
                       float* __restrict__ W1T,   float* __restrict__ fc1T) {
  int tid = blockIdx.x * blockDim.x + threadIdx.x;
  int nt = gridDim.x * blockDim.x;
  for (int i = tid; i < G3 * EE; i += nt) { int r = i / EE, c = i - r * EE; Wih0T[c * G3 + r] = Wih0[i]; }
  for (int i = tid; i < G3 * HH; i += nt) { int r = i / HH, c = i - r * HH; Whh0T[c * G3 + r] = Whh0[i]; }
  for (int i = tid; i < G3 * HH; i += nt) { int r = i / HH, c = i - r * HH; Wih1T[c * G3 + r] = Wih1[i]; }
  for (int i = tid; i < G3 * HH; i += nt) { int r = i / HH, c = i - r * HH; Whh1T[c * G3 + r] = Whh1[i]; }
  for (int i = tid; i < AT * HH; i += nt) { int r = i / HH, c = i - r * HH; W1T[c * AT + r] = W1[i]; }
  for (int i = tid; i < HH * HH; i += nt) { int r = i / HH, c = i - r * HH; fc1T[c * HH + r] = fc1w[i]; }
}

// ---------------- layer-0 input projection: gather + [32768,300]@[300,450] ----------------
__global__ __launch_bounds__(512) void k_xw0(const int* __restrict__ texts,
                                             const float* __restrict__ emb,
                                             const float* __restrict__ WihT,
                                             const float* __restrict__ bih,
                                             float* __restrict__ xw) {
  __shared__ __align__(16) float a_lds[32 * EE];
  const int row0 = blockIdx.x * 32;
  const int tid = threadIdx.x;
  for (int p = tid; p < 32 * EE; p += 512) {
    int r = p / EE, e = p - r * EE;
    int vrow = texts[row0 + r];
    a_lds[p] = emb[(size_t)vrow * EE + e];
  }
  __syncthreads();
  const int g = tid;
  if (g < G3) {
    float acc[32];
#pragma unroll
    for (int r = 0; r < 32; ++r) acc[r] = 0.f;
    const float bias = bih[g];
    for (int k = 0; k < EE; k += 4) {
      float w0 = WihT[(k + 0) * G3 + g];
      float w1 = WihT[(k + 1) * G3 + g];
      float w2v = WihT[(k + 2) * G3 + g];
      float w3 = WihT[(k + 3) * G3 + g];
#pragma unroll
      for (int r = 0; r < 32; ++r) {
        const float4 av = *reinterpret_cast<const float4*>(&a_lds[r * EE + k]);
        acc[r] = fmaf(av.x, w0, acc[r]);
        acc[r] = fmaf(av.y, w1, acc[r]);
        acc[r] = fmaf(av.z, w2v, acc[r]);
        acc[r] = fmaf(av.w, w3, acc[r]);
      }
    }
#pragma unroll
    for (int r = 0; r < 32; ++r) xw[(size_t)(row0 + r) * G3 + g] = acc[r] + bias;
  }
}

// ---------------- layer-1 input projection: [32768,150]@[150,450] ----------------
__global__ __launch_bounds__(512) void k_xw1(const float* __restrict__ in,
                                             const float* __restrict__ WihT,
                                             const float* __restrict__ bih,
                                             float* __restrict__ xw) {
  __shared__ __align__(16) float a_lds[32 * 152];
  const int row0 = blockIdx.x * 32;
  const int tid = threadIdx.x;
  for (int p = tid; p < 32 * HH; p += 512) {
    int r = p / HH, e = p - r * HH;
    a_lds[r * 152 + e] = in[(size_t)(row0 + r) * HH + e];
  }
  __syncthreads();
  const int g = tid;
  if (g < G3) {
    float acc[32];
#pragma unroll
    for (int r = 0; r < 32; ++r) acc[r] = 0.f;
    const float bias = bih[g];
    for (int k = 0; k < 148; k += 4) {
      float w0 = WihT[(k + 0) * G3 + g];
      float w1 = WihT[(k + 1) * G3 + g];
      float w2v = WihT[(k + 2) * G3 + g];
      float w3 = WihT[(k + 3) * G3 + g];
#pragma unroll
      for (int r = 0; r < 32; ++r) {
        const float4 av = *reinterpret_cast<const float4*>(&a_lds[r * 152 + k]);
        acc[r] = fmaf(av.x, w0, acc[r]);
        acc[r] = fmaf(av.y, w1, acc[r]);
        acc[r] = fmaf(av.z, w2v, acc[r]);
        acc[r] = fmaf(av.w, w3, acc[r]);
      }
    }
    {
      float w0 = WihT[148 * G3 + g];
      float w1 = WihT[149 * G3 + g];
#pragma unroll
      for (int r = 0; r < 32; ++r) {
        acc[r] = fmaf(a_lds[r * 152 + 148], w0, acc[r]);
        acc[r] = fmaf(a_lds[r * 152 + 149], w1, acc[r]);
      }
    }
#pragma unroll
    for (int r = 0; r < 32; ++r) xw[(size_t)(row0 + r) * G3 + g] = acc[r] + bias;
  }
}

// ---------------- GRU recurrence: one block per batch element ----------------
__global__ __launch_bounds__(512) void k_rec(const float* __restrict__ WhhT,
                                             const float* __restrict__ bhh,
                                             const float* __restrict__ xw,
                                             const int* __restrict__ lengths,
                                             float* __restrict__ out) {
  const int b = blockIdx.x;
  const int tid = threadIdx.x;
  __shared__ __align__(16) float h_lds[152];
  __shared__ float hg_lds[G3];
  const int len = lengths[b];

  float w[HH];
  float bias = 0.f;
  if (tid < G3) {
    bias = bhh[tid];
#pragma unroll
    for (int k = 0; k < HH; ++k) w[k] = WhhT[k * G3 + tid];
  }
  if (tid < 152) h_lds[tid] = 0.f;
  __syncthreads();

  const float* xwb = xw + (size_t)b * TT * G3;
  float* outb = out + (size_t)b * TT * HH;

  for (int t = 0; t < len; ++t) {
    float xr = 0.f, xz = 0.f, xn = 0.f;
    if (tid < HH) {
      const float* xwt = xwb + (size_t)t * G3;
      xr = xwt[tid]; xz = xwt[tid + HH]; xn = xwt[tid + 2 * HH];
    }
    if (tid < G3) {
      float a0 = bias, a1 = 0.f, a2 = 0.f, a3 = 0.f;
#pragma unroll
      for (int kk = 0; kk < 9; ++kk) {
        const int k0 = kk * 16;
        const float4 h0 = *reinterpret_cast<const float4*>(&h_lds[k0]);
        const float4 h1 = *reinterpret_cast<const float4*>(&h_lds[k0 + 4]);
        const float4 h2 = *reinterpret_cast<const float4*>(&h_lds[k0 + 8]);
        const float4 h3 = *reinterpret_cast<const float4*>(&h_lds[k0 + 12]);
        a0 = fmaf(w[k0 + 0], h0.x, a0); a0 = fmaf(w[k0 + 1], h0.y, a0);
        a0 = fmaf(w[k0 + 2], h0.z, a0); a0 = fmaf(w[k0 + 3], h0.w, a0);
        a1 = fmaf(w[k0 + 4], h1.x, a1); a1 = fmaf(w[k0 + 5], h1.y, a1);
        a1 = fmaf(w[k0 + 6], h1.z, a1); a1 = fmaf(w[k0 + 7], h1.w, a1);
        a2 = fmaf(w[k0 + 8], h2.x, a2); a2 = fmaf(w[k0 + 9], h2.y, a2);
        a2 = fmaf(w[k0 + 10], h2.z, a2); a2 = fmaf(w[k0 + 11], h2.w, a2);
        a3 = fmaf(w[k0 + 12], h3.x, a3); a3 = fmaf(w[k0 + 13], h3.y, a3);
        a3 = fmaf(w[k0 + 14], h3.z, a3); a3 = fmaf(w[k0 + 15], h3.w, a3);
      }
      { // k = 144..149
        const float4 hv = *reinterpret_cast<const float4*>(&h_lds[144]);
        a0 = fmaf(w[144], hv.x, a0); a1 = fmaf(w[145], hv.y, a1);
        a2 = fmaf(w[146], hv.z, a2); a3 = fmaf(w[147], hv.w, a3);
        a0 = fmaf(w[148], h_lds[148], a0);
        a1 = fmaf(w[149], h_lds[149], a1);
      }
      hg_lds[tid] = (a0 + a1) + (a2 + a3);
    }
    __syncthreads();
    if (tid < HH) {
      const float hr = hg_lds[tid], hz = hg_lds[tid + HH], hn = hg_lds[tid + 2 * HH];
      const float r = sigmoid_f(xr + hr);
      const float z = sigmoid_f(xz + hz);
      const float n = tanh_f(xn + r * hn);
      const float hold = h_lds[tid];
      const float hnew = (1.f - z) * n + z * hold;
      h_lds[tid] = hnew;
      outb[(size_t)t * HH + tid] = hnew;
    }
    __syncthreads();
  }
  // pad_packed_sequence pads with zeros past length
  const int rem = (TT - len) * HH;
  float* outp = outb + (size_t)len * HH;
  for (int p = tid; p < rem; p += 512) outp[p] = 0.f;
}

// ---------------- attention scores: tanh(out1 @ W1^T) @ w2^T ----------------
__global__ __launch_bounds__(256) void k_scores(const float* __restrict__ out1,
                                                const float* __restrict__ W1T,
                                                const float* __restrict__ w2,
                                                float* __restrict__ scores) {
  const int row0 = blockIdx.x * 32;
  const int tid = threadIdx.x;
  __shared__ float sc[32];
  if (tid < 32) sc[tid] = 0.f;
  __syncthreads();
  for (int p = tid; p < 32 * AT; p += 256) {
    const int r = p / AT, a = p - r * AT;
    const float* x = out1 + (size_t)(row0 + r) * HH;
    float a0 = 0.f, a1 = 0.f;
    for (int k = 0; k < HH; k += 2) {
      a0 = fmaf(W1T[k * AT + a], x[k], a0);
      a1 = fmaf(W1T[(k + 1) * AT + a], x[k + 1], a1);
    }
    atomicAdd(&sc[r], tanh_f(a0 + a1) * w2[a]);
  }
  __syncthreads();
  if (tid < 32) scores[row0 + tid] = sc[tid];
}

// ---------------- softmax + context + classifier head (per batch) ----------------
__global__ __launch_bounds__(512) void k_final(const float* __restrict__ out1,
                                               const float* __restrict__ scores,
                                               const float* __restrict__ fc1T,
                                               const float* __restrict__ fc1b,
                                               const float* __restrict__ fc2w,
                                               const float* __restrict__ fc2b,
                                               float* __restrict__ logits) {
  const int b = blockIdx.x;
  const int tid = threadIdx.x;
  __shared__ float attn[TT];
  __shared__ float red[16];
  __shared__ float ctx[152];
  __shared__ float h1[152];

  float s = scores[b * TT + tid];
  float m = s;
#pragma unroll
  for (int off = 32; off > 0; off >>= 1) m = fmaxf(m, __shfl_xor(m, off));
  const int wave = tid >> 6;
  if ((tid & 63) == 0) red[wave] = m;
  __syncthreads();
  if (tid == 0) {
    float mm = red[0];
#pragma unroll
    for (int i = 1; i < 8; ++i) mm = fmaxf(mm, red[i]);
    red[8] = mm;
  }
  __syncthreads();
  const float mx = red[8];
  const float e = __expf(s - mx);
  attn[tid] = e;
  float zz = e;
#pragma unroll
  for (int off = 32; off > 0; off >>= 1) zz += __shfl_xor(zz, off);
  if ((tid & 63) == 0) red[wave] = zz;
  __syncthreads();
  if (tid == 0) {
    float ss = 0.f;
#pragma unroll
    for (int i = 0; i < 8; ++i) ss += red[i];
    red[9] = ss;
  }
  __syncthreads();
  const float invZ = 1.f / red[9];

  if (tid < HH) {
    const float* o1b = out1 + (size_t)b * TT * HH;
    float c0 = 0.f, c1 = 0.f, c2 = 0.f, c3 = 0.f;
    for (int t = 0; t < TT; t += 4) {
      c0 = fmaf(attn[t + 0], o1b[(t + 0) * HH + tid], c0);
      c1 = fmaf(attn[t + 1], o1b[(t + 1) * HH + tid], c1);
      c2 = fmaf(attn[t + 2], o1b[(t + 2) * HH + tid], c2);
      c3 = fmaf(attn[t + 3], o1b[(t + 3) * HH + tid], c3);
    }
    ctx[tid] = ((c0 + c1) + (c2 + c3)) * invZ;
  }
  __syncthreads();
  if (tid < HH) {
    float d0 = 0.f, d1 = 0.f;
    for (int k = 0; k < HH; k += 2) {
      d0 = fmaf(fc1T[k * HH + tid], ctx[k], d0);
      d1 = fmaf(fc1T[(k + 1) * HH + tid], ctx[k + 1], d1);
    }
    h1[tid] = fmaxf(d0 + d1 + fc1b[tid], 0.f);
  }
  __syncthreads();
  if (tid == 0) {
    float acc = fc2b[0];
    for (int k = 0; k < HH; ++k) acc = fmaf(fc2w[k], h1[k], acc);
    logits[b] = acc;
  }
}

extern "C" void kernel_launch(void* const* d_in, const int* in_sizes, int n_in,
                              void* d_out, int out_size, void* d_ws, size_t ws_size,
                              hipStream_t stream) {
  const int* texts     = (const int*)d_in[0];
  const int* lengths   = (const int*)d_in[1];
  const float* emb     = (const float*)d_in[2];
  const float* Wih0    = (const float*)d_in[3];
  const float* Whh0    = (const float*)d_in[4];
  const float* bih0    = (const float*)d_in[5];
  const float* bhh0    = (const float*)d_in[6];
  const float* Wih1    = (const float*)d_in[7];
  const float* Whh1    = (const float*)d_in[8];
  const float* bih1    = (const float*)d_in[9];
  const float* bhh1    = (const float*)d_in[10];
  const float* W1      = (const float*)d_in[11];
  const float* w2      = (const float*)d_in[12];
  const float* fc1w    = (const float*)d_in[13];
  const float* fc1b    = (const float*)d_in[14];
  const float* fc2w    = (const float*)d_in[15];
  const float* fc2b    = (const float*)d_in[16];
  float* logits = (float*)d_out;

  float* ws = (float*)d_ws;
  size_t off = 0;
  auto alloc = [&](size_t n) { float* p = ws + off; off += (n + 3) & ~(size_t)3; return p; };
  float* Wih0T  = alloc((size_t)G3 * EE);
  float* Whh0T  = alloc((size_t)G3 * HH);
  float* Wih1T  = alloc((size_t)G3 * HH);
  float* Whh1T  = alloc((size_t)G3 * HH);
  float* W1T    = alloc((size_t)AT * HH);
  float* fc1T   = alloc((size_t)HH * HH);
  float* xwbuf  = alloc((size_t)BB * TT * G3);   // reused for xw0 then xw1
  float* out0   = alloc((size_t)BB * TT * HH);
  float* out1   = alloc((size_t)BB * TT * HH);
  float* scores = alloc((size_t)BB * TT);
  (void)ws_size; (void)in_sizes; (void)n_in; (void)out_size;

  hipLaunchKernelGGL(k_prep, dim3(256), dim3(256), 0, stream,
                     Wih0, Whh0, Wih1, Whh1, W1, fc1w,
                     Wih0T, Whh0T, Wih1T, Whh1T, W1T, fc1T);
  hipLaunchKernelGGL(k_xw0, dim3((BB * TT) / 32), dim3(512), 0, stream, texts, emb, Wih0T, bih0, xwbuf);
  hipLaunchKernelGGL(k_rec, dim3(BB), dim3(512), 0, stream, Whh0T, bhh0, xwbuf, lengths, out0);
  hipLaunchKernelGGL(k_xw1, dim3((BB * TT) / 32), dim3(512), 0, stream, out0, Wih1T, bih1, xwbuf);
  hipLaunchKernelGGL(k_rec, dim3(BB), dim3(512), 0, stream, Whh1T, bhh1, xwbuf, lengths, out1);
  hipLaunchKernelGGL(k_scores, dim3((BB * TT) / 32), dim3(256), 0, stream, out1, W1T, w2, scores);
  hipLaunchKernelGGL(k_final, dim3(BB), dim3(512), 0, stream, out1, scores, fc1T, fc1b, fc2w, fc2b, logits);
}